// Round 6
// baseline (511.942 us; speedup 1.0000x reference)
//
#include <hip/hip_runtime.h>
#include <hip/hip_bf16.h>
#include <stdint.h>
#include <stddef.h>

#define T_STEPS 28
#define I_DIM 28
#define H_DIM 64
#define O_DIM 10
#define BT 16          // batch rows per block = per wave
#define NTHREADS 64    // ONE wave per block: recurrence is wave-private, ZERO barriers

typedef short bf16x8  __attribute__((ext_vector_type(8)));
typedef float f32x4   __attribute__((ext_vector_type(4)));

// exp2 scale constants folded into weights:
//   sigmoid(z) = rcp(1 + exp2(-log2e * z))      -> scale i,f,o rows by KS
//   tanh(z)    = 1 - 2*rcp(1 + exp2(2*log2e*z)) -> scale g rows by KG
#define KS (-1.4426950408889634f)
#define KG ( 2.8853900817779268f)

__device__ __forceinline__ short f2bf(float f){
    uint32_t u = __builtin_bit_cast(uint32_t, f);
    u = (u + 0x7fffu + ((u >> 16) & 1u)) >> 16;
    return (short)u;
}
__device__ __forceinline__ float bf2f(short v){
    return __builtin_bit_cast(float, (uint32_t)(uint16_t)v << 16);
}
// packed f32x2 -> bf16x2 (RNE) as raw bits
__device__ __forceinline__ uint32_t pack_bf16x2(float lo, float hi){
    float2 p2; p2.x = lo; p2.y = hi;
    __hip_bfloat162 p = __float22bfloat162_rn(p2);
    uint32_t u;
    __builtin_memcpy(&u, &p, 4);
    return u;
}

// LDS layout (bytes):
//   wih frags: [16 tiles][64 lanes][16B]  = 16384 @ 0   (pre-swizzled B-frag layout,
//              bias folded at k==28; read-only after staging -> no barrier needed)
//   h buffer:  short[16][72]              =  2304 @ 16384 (single buffer: within one
//              wave, write h(t+1) then read it -- lgkmcnt orders, no double-buffer)
#define WIH_OFF 0
#define H_OFF   16384
#define SMEM_BYTES (16384 + 2304)

__global__ __launch_bounds__(NTHREADS, 2)   // 2 waves/EU -> 256-reg cap
void lstm_fused(const float* __restrict__ x,
                const float* __restrict__ W_ih,
                const float* __restrict__ W_hh,
                const float* __restrict__ b_ih,
                const float* __restrict__ b_hh,
                const float* __restrict__ W_out,
                const float* __restrict__ b_out,
                float* __restrict__ out)
{
    __shared__ alignas(16) unsigned char smem[SMEM_BYTES];
    short* wihs = (short*)(smem + WIH_OFF);
    short (*hbuf)[72] = (short(*)[72])(smem + H_OFF);

    const int lane = threadIdx.x;      // single wave: 0..63
    const int col  = lane & 15;        // batch row within tile / gate col within tile
    const int quad = lane >> 4;
    const int b0   = blockIdx.x * BT;

    // ---- stage W_ih B-frags into LDS, pre-swizzled, scaled; bias at k==28 ----
    // B[k][n] frag for tile: lane holds n = tile*16 + col, k = quad*8 + j.
    #pragma unroll
    for (int tile = 0; tile < 16; ++tile){
        const float sc = (tile >= 8 && tile < 12) ? KG : KS;   // tiles 8..11 = g gate
        const int n = tile * 16 + col;
        const float* wr = W_ih + n * I_DIM;
        bf16x8 fv;
        #pragma unroll
        for (int j = 0; j < 8; ++j){
            const int k = quad * 8 + j;
            const float v = (k < I_DIM) ? wr[k]
                          : (k == I_DIM) ? (b_ih[n] + b_hh[n])
                          : 0.0f;
            fv[j] = f2bf(sc * v);
        }
        *(bf16x8*)&wihs[(tile * 64 + lane) * 8] = fv;    // one ds_write_b128
    }

    // ---- W_hh B-frags in registers (128 VGPRs), scaled ----
    bf16x8 whh[16][2];
    #pragma unroll
    for (int tile = 0; tile < 16; ++tile){
        const float sc = (tile >= 8 && tile < 12) ? KG : KS;
        const int n = tile * 16 + col;
        const float* wr = W_hh + n * H_DIM;
        #pragma unroll
        for (int s = 0; s < 2; ++s){
            bf16x8 fv;
            #pragma unroll
            for (int j = 0; j < 8; ++j)
                fv[j] = f2bf(sc * wr[s * 32 + quad * 8 + j]);
            whh[tile][s] = fv;
        }
    }
    const f32x4 z4 = {0.0f, 0.0f, 0.0f, 0.0f};

    // ---- x direct from global, one step prefetched ----
    // A-frag: lane needs x[b0+col][t][quad*8 .. +7]; quad 3 covers k=24..27 from
    // memory, k=28 = constant 1.0 (multiplies folded bias row), k=29..31 = 0.
    const float* px = x + (size_t)(b0 + col) * (T_STEPS * I_DIM) + quad * 8;
    float4 xva = *(const float4*)px;
    float4 xvb;
    if (quad < 3) xvb = *(const float4*)(px + 4);
    else          { xvb.x = 1.0f; xvb.y = 0.0f; xvb.z = 0.0f; xvb.w = 0.0f; }

    bf16x8 ha{}, hb{};       // h(0) = 0 (A-frags, k=0..31 / 32..63)
    float cst[4][4];         // cell state: [hidden group g][batch row r]
    #pragma unroll
    for (int g = 0; g < 4; ++g)
        #pragma unroll
        for (int r = 0; r < 4; ++r) cst[g][r] = 0.0f;

    for (int t = 0; t < T_STEPS; ++t){
        // build x A-frag from prefetched regs
        uint4 uu;
        uu.x = pack_bf16x2(xva.x, xva.y);
        uu.y = pack_bf16x2(xva.z, xva.w);
        uu.z = pack_bf16x2(xvb.x, xvb.y);
        uu.w = pack_bf16x2(xvb.z, xvb.w);
        bf16x8 xf; __builtin_memcpy(&xf, &uu, 16);

        // prefetch x(t+1): in flight across the whole step's compute
        if (t < T_STEPS - 1){
            px += I_DIM;
            xva = *(const float4*)px;
            if (quad < 3) xvb = *(const float4*)(px + 4);
        }

        // 4 hidden-groups: tiles {g, 4+g, 8+g, 12+g} = gates i,f,g,o of hidden
        // 16g..16g+15. Only 4 acc tiles (16 regs) live at a time.
        #pragma unroll
        for (int g = 0; g < 4; ++g){
            f32x4 acc[4];
            #pragma unroll
            for (int gi = 0; gi < 4; ++gi){
                const int tile = gi * 4 + g;
                bf16x8 wf;
                __builtin_memcpy(&wf, &wihs[(tile * 64 + lane) * 8], 16); // ds_read_b128
                f32x4 a = __builtin_amdgcn_mfma_f32_16x16x32_bf16(xf, wf, z4, 0, 0, 0);
                a = __builtin_amdgcn_mfma_f32_16x16x32_bf16(ha, whh[tile][0], a, 0, 0, 0);
                a = __builtin_amdgcn_mfma_f32_16x16x32_bf16(hb, whh[tile][1], a, 0, 0, 0);
                acc[gi] = a;
            }
            // activations (paired reciprocals): element = (batch 4*quad+r, hidden 16g+col)
            // Trans/elem: 5 exp2 + 2.5 rcp.
            float hv[4];
            #pragma unroll
            for (int p = 0; p < 2; ++p){
                const int r0 = 2 * p, r1 = 2 * p + 1;
                const float dA0 = 1.0f + __builtin_amdgcn_exp2f(acc[0][r0]);
                const float dA1 = 1.0f + __builtin_amdgcn_exp2f(acc[0][r1]);
                const float dB0 = 1.0f + __builtin_amdgcn_exp2f(acc[1][r0]);
                const float dB1 = 1.0f + __builtin_amdgcn_exp2f(acc[1][r1]);
                const float R10 = __builtin_amdgcn_rcpf(dA0 * dB0);
                const float R11 = __builtin_amdgcn_rcpf(dA1 * dB1);
                const float iv0 = R10 * dB0, fv0 = R10 * dA0;
                const float iv1 = R11 * dB1, fv1 = R11 * dA1;
                const float dG0 = 1.0f + __builtin_amdgcn_exp2f(acc[2][r0]);
                const float dG1 = 1.0f + __builtin_amdgcn_exp2f(acc[2][r1]);
                const float dO0 = 1.0f + __builtin_amdgcn_exp2f(acc[3][r0]);
                const float dO1 = 1.0f + __builtin_amdgcn_exp2f(acc[3][r1]);
                const float R20 = __builtin_amdgcn_rcpf(dG0 * dO0);
                const float R21 = __builtin_amdgcn_rcpf(dG1 * dO1);
                const float ov0 = R20 * dG0, ov1 = R21 * dG1;
                const float gv0 = 1.0f - 2.0f * (R20 * dO0);
                const float gv1 = 1.0f - 2.0f * (R21 * dO1);
                const float c0 = fv0 * cst[g][r0] + iv0 * gv0;
                const float c1 = fv1 * cst[g][r1] + iv1 * gv1;
                cst[g][r0] = c0; cst[g][r1] = c1;
                const float d50 = 1.0f + __builtin_amdgcn_exp2f(KG * c0);
                const float d51 = 1.0f + __builtin_amdgcn_exp2f(KG * c1);
                const float R5 = __builtin_amdgcn_rcpf(d50 * d51);
                const float t2 = 2.0f * R5;
                hv[r0] = ov0 * (1.0f - t2 * d51);
                hv[r1] = ov1 * (1.0f - t2 * d50);
            }
            // scatter h(t+1) -> LDS (one addr reg + compile-time offsets; ~2-way banks)
            #pragma unroll
            for (int rp = 0; rp < 2; ++rp){
                const uint32_t u2 = pack_bf16x2(hv[2 * rp], hv[2 * rp + 1]);
                hbuf[4 * quad + 2 * rp    ][16 * g + col] = (short)(u2 & 0xffffu);
                hbuf[4 * quad + 2 * rp + 1][16 * g + col] = (short)(u2 >> 16);
            }
        }
        // read h(t+1) A-frags for next step. Same wave wrote them: lgkmcnt
        // ordering suffices -- NO barrier anywhere in this loop.
        __builtin_memcpy(&ha, &hbuf[col][quad * 8],      16);
        __builtin_memcpy(&hb, &hbuf[col][32 + quad * 8], 16);
    }

    // ---- output projection from final h (in hbuf; same wave -> no barrier) ----
    for (int idx = lane; idx < BT * O_DIM; idx += NTHREADS){
        const int m = idx / O_DIM;
        const int o = idx - m * O_DIM;
        float s = b_out[o];
        #pragma unroll 8
        for (int j = 0; j < H_DIM; ++j)
            s += bf2f(hbuf[m][j]) * W_out[o * H_DIM + j];
        out[(size_t)b0 * O_DIM + idx] = s;
    }
}

extern "C" void kernel_launch(void* const* d_in, const int* in_sizes, int n_in,
                              void* d_out, int out_size, void* d_ws, size_t ws_size,
                              hipStream_t stream) {
    const float* x     = (const float*)d_in[0];
    const float* W_ih  = (const float*)d_in[1];
    const float* W_hh  = (const float*)d_in[2];
    const float* b_ih  = (const float*)d_in[3];
    const float* b_hh  = (const float*)d_in[4];
    const float* W_out = (const float*)d_in[5];
    const float* b_out = (const float*)d_in[6];
    float* out = (float*)d_out;

    const int grid = 65536 / BT;   // 4096 blocks x 64 threads (1 wave each)
    lstm_fused<<<grid, NTHREADS, 0, stream>>>(x, W_ih, W_hh, b_ih, b_hh, W_out, b_out, out);
}

// Round 7
// 416.567 us; speedup vs baseline: 1.2290x; 1.2290x over previous
//
#include <hip/hip_runtime.h>
#include <hip/hip_bf16.h>
#include <stdint.h>
#include <stddef.h>

#define T_STEPS 28
#define I_DIM 28
#define H_DIM 64
#define O_DIM 10
#define BT 64          // 4 waves x 16 rows; each wave's recurrence is private
#define NTHREADS 256

typedef short bf16x8  __attribute__((ext_vector_type(8)));
typedef float f32x4   __attribute__((ext_vector_type(4)));

// exp2 scale constants folded into weights:
//   sigmoid(z) = rcp(1 + exp2(-log2e * z))      -> scale i,f,o rows by KS
//   tanh(z)    = 1 - 2*rcp(1 + exp2(2*log2e*z)) -> scale g rows by KG
#define KS (-1.4426950408889634f)
#define KG ( 2.8853900817779268f)

__device__ __forceinline__ short f2bf(float f){
    uint32_t u = __builtin_bit_cast(uint32_t, f);
    u = (u + 0x7fffu + ((u >> 16) & 1u)) >> 16;
    return (short)u;
}
__device__ __forceinline__ float bf2f(short v){
    return __builtin_bit_cast(float, (uint32_t)(uint16_t)v << 16);
}
// packed f32x2 -> bf16x2 (RNE) as raw bits
__device__ __forceinline__ uint32_t pack_bf16x2(float lo, float hi){
    float2 p2; p2.x = lo; p2.y = hi;
    __hip_bfloat162 p = __float22bfloat162_rn(p2);
    uint32_t u;
    __builtin_memcpy(&u, &p, 4);
    return u;
}

// LDS layout (bytes):
//   wih frags: [16 tiles][64 lanes][16B]      = 16384 @ 0      (bias folded at k==28)
//   whh frags: [2 s][16 tiles][64 lanes][16B] = 32768 @ 16384
//   h buffers: 4 waves x short[16][72]        =  9216 @ 49152  (wave-private: same
//              wave writes then reads -- lgkmcnt orders it, NO barrier in t-loop)
#define WIH_OFF 0
#define WHH_OFF 16384
#define HB_OFF  49152
#define SMEM_BYTES (49152 + 4 * 2304)

__global__ __launch_bounds__(NTHREADS, 2)   // 256-reg cap: never spill; LDS binds occupancy
void lstm_fused(const float* __restrict__ x,
                const float* __restrict__ W_ih,
                const float* __restrict__ W_hh,
                const float* __restrict__ b_ih,
                const float* __restrict__ b_hh,
                const float* __restrict__ W_out,
                const float* __restrict__ b_out,
                float* __restrict__ out)
{
    __shared__ alignas(16) unsigned char smem[SMEM_BYTES];
    short* wihs = (short*)(smem + WIH_OFF);
    short* whhs = (short*)(smem + WHH_OFF);

    const int tid  = threadIdx.x;
    const int w    = tid >> 6;         // wave 0..3
    const int lane = tid & 63;
    const int col  = lane & 15;
    const int quad = lane >> 4;
    const int b0   = blockIdx.x * BT;
    const int rb   = b0 + w * 16;      // this wave's 16 batch rows

    short (*hbuf)[72] = (short(*)[72])(smem + HB_OFF + w * 2304);

    // ---- stage weight B-frags into LDS (4 tiles per wave), pre-scaled ----
    // frag for tile: lane holds n = tile*16 + col, k = quad*8 + j.
    #pragma unroll
    for (int i = 0; i < 4; ++i){
        const int tile = w * 4 + i;
        const float sc = (tile >= 8 && tile < 12) ? KG : KS;   // tiles 8..11 = g gate
        const int n = tile * 16 + col;
        {
            const float* wr = W_ih + n * I_DIM;
            bf16x8 fv;
            #pragma unroll
            for (int j = 0; j < 8; ++j){
                const int k = quad * 8 + j;
                const float v = (k < I_DIM) ? wr[k]
                              : (k == I_DIM) ? (b_ih[n] + b_hh[n])
                              : 0.0f;
                fv[j] = f2bf(sc * v);
            }
            *(bf16x8*)&wihs[(tile * 64 + lane) * 8] = fv;
        }
        const float* hr = W_hh + n * H_DIM;
        #pragma unroll
        for (int s = 0; s < 2; ++s){
            bf16x8 fv;
            #pragma unroll
            for (int j = 0; j < 8; ++j)
                fv[j] = f2bf(sc * hr[s * 32 + quad * 8 + j]);
            *(bf16x8*)&whhs[((s * 16 + tile) * 64 + lane) * 8] = fv;
        }
    }
    __syncthreads();   // the ONLY barrier: weights visible to all 4 waves

    const f32x4 z4 = {0.0f, 0.0f, 0.0f, 0.0f};

    // ---- x direct from global, one step prefetched ----
    // A-frag: lane needs x[rb+col][t][quad*8 .. +7]; quad 3: k=24..27 from memory,
    // k=28 = constant 1.0 (multiplies folded bias row), k=29..31 = 0.
    const float* px = x + (size_t)(rb + col) * (T_STEPS * I_DIM) + quad * 8;
    float4 xva = *(const float4*)px;
    float4 xvb;
    if (quad < 3) xvb = *(const float4*)(px + 4);
    else          { xvb.x = 1.0f; xvb.y = 0.0f; xvb.z = 0.0f; xvb.w = 0.0f; }

    bf16x8 ha{}, hb{};       // h(0) = 0 (A-frags, k=0..31 / 32..63)
    float cst[4][4];         // cell state: [hidden group g][row r]
    #pragma unroll
    for (int g = 0; g < 4; ++g)
        #pragma unroll
        for (int r = 0; r < 4; ++r) cst[g][r] = 0.0f;

    for (int t = 0; t < T_STEPS; ++t){
        // build x A-frag from prefetched regs
        uint4 uu;
        uu.x = pack_bf16x2(xva.x, xva.y);
        uu.y = pack_bf16x2(xva.z, xva.w);
        uu.z = pack_bf16x2(xvb.x, xvb.y);
        uu.w = pack_bf16x2(xvb.z, xvb.w);
        bf16x8 xf; __builtin_memcpy(&xf, &uu, 16);

        // prefetch x(t+1): stays in flight across the whole step (no barrier drains it)
        if (t < T_STEPS - 1){
            px += I_DIM;
            xva = *(const float4*)px;
            if (quad < 3) xvb = *(const float4*)(px + 4);
        }

        // 4 hidden-groups: tiles {g, 4+g, 8+g, 12+g} = gates i,f,g,o of hidden
        // 16g..16g+15. Only 4 acc tiles live at a time. Weight frags from LDS.
        #pragma unroll
        for (int g = 0; g < 4; ++g){
            f32x4 acc[4];
            #pragma unroll
            for (int gi = 0; gi < 4; ++gi){
                const int tile = gi * 4 + g;
                bf16x8 wf, w0, w1;
                __builtin_memcpy(&wf, &wihs[(tile * 64 + lane) * 8], 16);
                __builtin_memcpy(&w0, &whhs[(tile * 64 + lane) * 8], 16);
                __builtin_memcpy(&w1, &whhs[((16 + tile) * 64 + lane) * 8], 16);
                f32x4 a = __builtin_amdgcn_mfma_f32_16x16x32_bf16(xf, wf, z4, 0, 0, 0);
                a = __builtin_amdgcn_mfma_f32_16x16x32_bf16(ha, w0, a, 0, 0, 0);
                a = __builtin_amdgcn_mfma_f32_16x16x32_bf16(hb, w1, a, 0, 0, 0);
                acc[gi] = a;
            }
            // activations (paired reciprocals): element = (row 4*quad+r, hidden 16g+col)
            // Trans/elem: 5 exp2 + 2.5 rcp.
            float hv[4];
            #pragma unroll
            for (int p = 0; p < 2; ++p){
                const int r0 = 2 * p, r1 = 2 * p + 1;
                const float dA0 = 1.0f + __builtin_amdgcn_exp2f(acc[0][r0]);
                const float dA1 = 1.0f + __builtin_amdgcn_exp2f(acc[0][r1]);
                const float dB0 = 1.0f + __builtin_amdgcn_exp2f(acc[1][r0]);
                const float dB1 = 1.0f + __builtin_amdgcn_exp2f(acc[1][r1]);
                const float R10 = __builtin_amdgcn_rcpf(dA0 * dB0);
                const float R11 = __builtin_amdgcn_rcpf(dA1 * dB1);
                const float iv0 = R10 * dB0, fv0 = R10 * dA0;
                const float iv1 = R11 * dB1, fv1 = R11 * dA1;
                const float dG0 = 1.0f + __builtin_amdgcn_exp2f(acc[2][r0]);
                const float dG1 = 1.0f + __builtin_amdgcn_exp2f(acc[2][r1]);
                const float dO0 = 1.0f + __builtin_amdgcn_exp2f(acc[3][r0]);
                const float dO1 = 1.0f + __builtin_amdgcn_exp2f(acc[3][r1]);
                const float R20 = __builtin_amdgcn_rcpf(dG0 * dO0);
                const float R21 = __builtin_amdgcn_rcpf(dG1 * dO1);
                const float ov0 = R20 * dG0, ov1 = R21 * dG1;
                const float gv0 = 1.0f - 2.0f * (R20 * dO0);
                const float gv1 = 1.0f - 2.0f * (R21 * dO1);
                const float c0 = fv0 * cst[g][r0] + iv0 * gv0;
                const float c1 = fv1 * cst[g][r1] + iv1 * gv1;
                cst[g][r0] = c0; cst[g][r1] = c1;
                const float d50 = 1.0f + __builtin_amdgcn_exp2f(KG * c0);
                const float d51 = 1.0f + __builtin_amdgcn_exp2f(KG * c1);
                const float R5 = __builtin_amdgcn_rcpf(d50 * d51);
                const float t2 = 2.0f * R5;
                hv[r0] = ov0 * (1.0f - t2 * d51);
                hv[r1] = ov1 * (1.0f - t2 * d50);
            }
            // scatter h(t+1) -> own h buffer (~2-way banks, free)
            #pragma unroll
            for (int rp = 0; rp < 2; ++rp){
                const uint32_t u2 = pack_bf16x2(hv[2 * rp], hv[2 * rp + 1]);
                hbuf[4 * quad + 2 * rp    ][16 * g + col] = (short)(u2 & 0xffffu);
                hbuf[4 * quad + 2 * rp + 1][16 * g + col] = (short)(u2 >> 16);
            }
        }
        // read h(t+1) A-frags for next step; same wave wrote them -> lgkmcnt
        // ordering suffices, no barrier.
        __builtin_memcpy(&ha, &hbuf[col][quad * 8],      16);
        __builtin_memcpy(&hb, &hbuf[col][32 + quad * 8], 16);
    }

    // ---- output projection from this wave's final h (wave-private, no barrier) ----
    for (int idx = lane; idx < 16 * O_DIM; idx += 64){
        const int m = idx / O_DIM;
        const int o = idx - m * O_DIM;
        float s = b_out[o];
        #pragma unroll 8
        for (int j = 0; j < H_DIM; ++j)
            s += bf2f(hbuf[m][j]) * W_out[o * H_DIM + j];
        out[(size_t)(rb + m) * O_DIM + o] = s;
    }
}

extern "C" void kernel_launch(void* const* d_in, const int* in_sizes, int n_in,
                              void* d_out, int out_size, void* d_ws, size_t ws_size,
                              hipStream_t stream) {
    const float* x     = (const float*)d_in[0];
    const float* W_ih  = (const float*)d_in[1];
    const float* W_hh  = (const float*)d_in[2];
    const float* b_ih  = (const float*)d_in[3];
    const float* b_hh  = (const float*)d_in[4];
    const float* W_out = (const float*)d_in[5];
    const float* b_out = (const float*)d_in[6];
    float* out = (float*)d_out;

    const int grid = 65536 / BT;   // 1024 blocks x 256 threads (4 waves)
    lstm_fused<<<grid, NTHREADS, 0, stream>>>(x, W_ih, W_hh, b_ih, b_hh, W_out, b_out, out);
}

// Round 8
// 381.535 us; speedup vs baseline: 1.3418x; 1.0918x over previous
//
#include <hip/hip_runtime.h>
#include <hip/hip_bf16.h>
#include <stdint.h>
#include <stddef.h>

#define T_STEPS 28
#define I_DIM 28
#define H_DIM 64
#define O_DIM 10
#define BT 128         // 8 waves x 16 rows; each wave's recurrence is private
#define NTHREADS 512   // one 48KB weight copy amortized over 8 waves -> 4 waves/SIMD

typedef short bf16x8  __attribute__((ext_vector_type(8)));
typedef float f32x4   __attribute__((ext_vector_type(4)));

// exp2 scale constants folded into weights:
//   sigmoid(z) = rcp(1 + exp2(-log2e * z))      -> scale i,f,o rows by KS
//   tanh(z)    = 1 - 2*rcp(1 + exp2(2*log2e*z)) -> scale g rows by KG
#define KS (-1.4426950408889634f)
#define KG ( 2.8853900817779268f)

__device__ __forceinline__ short f2bf(float f){
    uint32_t u = __builtin_bit_cast(uint32_t, f);
    u = (u + 0x7fffu + ((u >> 16) & 1u)) >> 16;
    return (short)u;
}
__device__ __forceinline__ float bf2f(short v){
    return __builtin_bit_cast(float, (uint32_t)(uint16_t)v << 16);
}
// packed f32x2 -> bf16x2 (RNE) as raw bits
__device__ __forceinline__ uint32_t pack_bf16x2(float lo, float hi){
    float2 p2; p2.x = lo; p2.y = hi;
    __hip_bfloat162 p = __float22bfloat162_rn(p2);
    uint32_t u;
    __builtin_memcpy(&u, &p, 4);
    return u;
}

// LDS layout (bytes):
//   wih frags: [16 tiles][64 lanes][16B]      = 16384 @ 0      (bias folded at k==28)
//   whh frags: [2 s][16 tiles][64 lanes][16B] = 32768 @ 16384
//   h buffers: 8 waves x short[16][72]        = 18432 @ 49152  (wave-private: same
//              wave writes then reads -- lgkmcnt orders it, NO barrier in t-loop)
// total 67584 B (gfx950 allows up to 160 KB per workgroup); 2 blocks/CU.
#define WIH_OFF 0
#define WHH_OFF 16384
#define HB_OFF  49152
#define SMEM_BYTES (49152 + 8 * 2304)

__global__ __launch_bounds__(NTHREADS, 4)   // 4 waves/EU -> 128-reg cap (we use ~88)
void lstm_fused(const float* __restrict__ x,
                const float* __restrict__ W_ih,
                const float* __restrict__ W_hh,
                const float* __restrict__ b_ih,
                const float* __restrict__ b_hh,
                const float* __restrict__ W_out,
                const float* __restrict__ b_out,
                float* __restrict__ out)
{
    __shared__ alignas(16) unsigned char smem[SMEM_BYTES];
    short* wihs = (short*)(smem + WIH_OFF);
    short* whhs = (short*)(smem + WHH_OFF);

    const int tid  = threadIdx.x;
    const int w    = tid >> 6;         // wave 0..7
    const int lane = tid & 63;
    const int col  = lane & 15;
    const int quad = lane >> 4;
    const int b0   = blockIdx.x * BT;
    const int rb   = b0 + w * 16;      // this wave's 16 batch rows

    short (*hbuf)[72] = (short(*)[72])(smem + HB_OFF + w * 2304);

    // ---- stage weight B-frags into LDS (2 tiles per wave), pre-scaled ----
    // frag for tile: lane holds n = tile*16 + col, k = quad*8 + j.
    #pragma unroll
    for (int i = 0; i < 2; ++i){
        const int tile = w * 2 + i;
        const float sc = (tile >= 8 && tile < 12) ? KG : KS;   // tiles 8..11 = g gate
        const int n = tile * 16 + col;
        {
            const float* wr = W_ih + n * I_DIM;
            bf16x8 fv;
            #pragma unroll
            for (int j = 0; j < 8; ++j){
                const int k = quad * 8 + j;
                const float v = (k < I_DIM) ? wr[k]
                              : (k == I_DIM) ? (b_ih[n] + b_hh[n])
                              : 0.0f;
                fv[j] = f2bf(sc * v);
            }
            *(bf16x8*)&wihs[(tile * 64 + lane) * 8] = fv;
        }
        const float* hr = W_hh + n * H_DIM;
        #pragma unroll
        for (int s = 0; s < 2; ++s){
            bf16x8 fv;
            #pragma unroll
            for (int j = 0; j < 8; ++j)
                fv[j] = f2bf(sc * hr[s * 32 + quad * 8 + j]);
            *(bf16x8*)&whhs[((s * 16 + tile) * 64 + lane) * 8] = fv;
        }
    }
    __syncthreads();   // the ONLY barrier: weights visible to all 8 waves

    const f32x4 z4 = {0.0f, 0.0f, 0.0f, 0.0f};

    // ---- x direct from global, one step prefetched ----
    // A-frag: lane needs x[rb+col][t][quad*8 .. +7]; quad 3: k=24..27 from memory,
    // k=28 = constant 1.0 (multiplies folded bias row), k=29..31 = 0.
    const float* px = x + (size_t)(rb + col) * (T_STEPS * I_DIM) + quad * 8;
    float4 xva = *(const float4*)px;
    float4 xvb;
    if (quad < 3) xvb = *(const float4*)(px + 4);
    else          { xvb.x = 1.0f; xvb.y = 0.0f; xvb.z = 0.0f; xvb.w = 0.0f; }

    bf16x8 ha{}, hb{};       // h(0) = 0 (A-frags, k=0..31 / 32..63)
    float cst[4][4];         // cell state: [hidden group g][row r]
    #pragma unroll
    for (int g = 0; g < 4; ++g)
        #pragma unroll
        for (int r = 0; r < 4; ++r) cst[g][r] = 0.0f;

    for (int t = 0; t < T_STEPS; ++t){
        // build x A-frag from prefetched regs
        uint4 uu;
        uu.x = pack_bf16x2(xva.x, xva.y);
        uu.y = pack_bf16x2(xva.z, xva.w);
        uu.z = pack_bf16x2(xvb.x, xvb.y);
        uu.w = pack_bf16x2(xvb.z, xvb.w);
        bf16x8 xf; __builtin_memcpy(&xf, &uu, 16);

        // prefetch x(t+1): stays in flight across the whole step (no barrier drains it)
        if (t < T_STEPS - 1){
            px += I_DIM;
            xva = *(const float4*)px;
            if (quad < 3) xvb = *(const float4*)(px + 4);
        }

        // 4 hidden-groups: tiles {g, 4+g, 8+g, 12+g} = gates i,f,g,o of hidden
        // 16g..16g+15. Only 4 acc tiles live at a time. Weight frags from LDS.
        #pragma unroll
        for (int g = 0; g < 4; ++g){
            f32x4 acc[4];
            #pragma unroll
            for (int gi = 0; gi < 4; ++gi){
                const int tile = gi * 4 + g;
                bf16x8 wf, w0, w1;
                __builtin_memcpy(&wf, &wihs[(tile * 64 + lane) * 8], 16);
                __builtin_memcpy(&w0, &whhs[(tile * 64 + lane) * 8], 16);
                __builtin_memcpy(&w1, &whhs[((16 + tile) * 64 + lane) * 8], 16);
                f32x4 a = __builtin_amdgcn_mfma_f32_16x16x32_bf16(xf, wf, z4, 0, 0, 0);
                a = __builtin_amdgcn_mfma_f32_16x16x32_bf16(ha, w0, a, 0, 0, 0);
                a = __builtin_amdgcn_mfma_f32_16x16x32_bf16(hb, w1, a, 0, 0, 0);
                acc[gi] = a;
            }
            // activations (paired reciprocals): element = (row 4*quad+r, hidden 16g+col)
            // Trans/elem: 5 exp2 + 2.5 rcp.
            float hv[4];
            #pragma unroll
            for (int p = 0; p < 2; ++p){
                const int r0 = 2 * p, r1 = 2 * p + 1;
                const float dA0 = 1.0f + __builtin_amdgcn_exp2f(acc[0][r0]);
                const float dA1 = 1.0f + __builtin_amdgcn_exp2f(acc[0][r1]);
                const float dB0 = 1.0f + __builtin_amdgcn_exp2f(acc[1][r0]);
                const float dB1 = 1.0f + __builtin_amdgcn_exp2f(acc[1][r1]);
                const float R10 = __builtin_amdgcn_rcpf(dA0 * dB0);
                const float R11 = __builtin_amdgcn_rcpf(dA1 * dB1);
                const float iv0 = R10 * dB0, fv0 = R10 * dA0;
                const float iv1 = R11 * dB1, fv1 = R11 * dA1;
                const float dG0 = 1.0f + __builtin_amdgcn_exp2f(acc[2][r0]);
                const float dG1 = 1.0f + __builtin_amdgcn_exp2f(acc[2][r1]);
                const float dO0 = 1.0f + __builtin_amdgcn_exp2f(acc[3][r0]);
                const float dO1 = 1.0f + __builtin_amdgcn_exp2f(acc[3][r1]);
                const float R20 = __builtin_amdgcn_rcpf(dG0 * dO0);
                const float R21 = __builtin_amdgcn_rcpf(dG1 * dO1);
                const float ov0 = R20 * dG0, ov1 = R21 * dG1;
                const float gv0 = 1.0f - 2.0f * (R20 * dO0);
                const float gv1 = 1.0f - 2.0f * (R21 * dO1);
                const float c0 = fv0 * cst[g][r0] + iv0 * gv0;
                const float c1 = fv1 * cst[g][r1] + iv1 * gv1;
                cst[g][r0] = c0; cst[g][r1] = c1;
                const float d50 = 1.0f + __builtin_amdgcn_exp2f(KG * c0);
                const float d51 = 1.0f + __builtin_amdgcn_exp2f(KG * c1);
                const float R5 = __builtin_amdgcn_rcpf(d50 * d51);
                const float t2 = 2.0f * R5;
                hv[r0] = ov0 * (1.0f - t2 * d51);
                hv[r1] = ov1 * (1.0f - t2 * d50);
            }
            // scatter h(t+1) -> own h buffer (~2-way banks, free)
            #pragma unroll
            for (int rp = 0; rp < 2; ++rp){
                const uint32_t u2 = pack_bf16x2(hv[2 * rp], hv[2 * rp + 1]);
                hbuf[4 * quad + 2 * rp    ][16 * g + col] = (short)(u2 & 0xffffu);
                hbuf[4 * quad + 2 * rp + 1][16 * g + col] = (short)(u2 >> 16);
            }
        }
        // read h(t+1) A-frags for next step; same wave wrote them -> lgkmcnt
        // ordering suffices, no barrier.
        __builtin_memcpy(&ha, &hbuf[col][quad * 8],      16);
        __builtin_memcpy(&hb, &hbuf[col][32 + quad * 8], 16);
    }

    // ---- output projection from this wave's final h (wave-private, no barrier) ----
    for (int idx = lane; idx < 16 * O_DIM; idx += 64){
        const int m = idx / O_DIM;
        const int o = idx - m * O_DIM;
        float s = b_out[o];
        #pragma unroll 8
        for (int j = 0; j < H_DIM; ++j)
            s += bf2f(hbuf[m][j]) * W_out[o * H_DIM + j];
        out[(size_t)(rb + m) * O_DIM + o] = s;
    }
}

extern "C" void kernel_launch(void* const* d_in, const int* in_sizes, int n_in,
                              void* d_out, int out_size, void* d_ws, size_t ws_size,
                              hipStream_t stream) {
    const float* x     = (const float*)d_in[0];
    const float* W_ih  = (const float*)d_in[1];
    const float* W_hh  = (const float*)d_in[2];
    const float* b_ih  = (const float*)d_in[3];
    const float* b_hh  = (const float*)d_in[4];
    const float* W_out = (const float*)d_in[5];
    const float* b_out = (const float*)d_in[6];
    float* out = (float*)d_out;

    const int grid = 65536 / BT;   // 512 blocks x 512 threads (8 waves)
    lstm_fused<<<grid, NTHREADS, 0, stream>>>(x, W_ih, W_hh, b_ih, b_hh, W_out, b_out, out);
}